// Round 11
// baseline (173.117 us; speedup 1.0000x reference)
//
#include <hip/hip_runtime.h>
#include <hip/hip_bf16.h>

// B=16,S=4096,H=512 ; G=2,V=320,D=256 (Dg=128)
constexpr int BT = 65536;
constexpr int K  = 512;
constexpr int V  = 320;
constexpr int G  = 2;
constexpr int Dg = 128;
constexpr int MT = 64;           // rows per block; 8 waves = 2 row-halves x 4 col-quarters
constexpr int NSTEP = 16;        // K/32
constexpr size_t WS_IMG   = 4096;            // frag-ordered B img (640 KB)
constexpr size_t WS_SINK1 = 659456;          // ablation sinks (64 KB each)
constexpr size_t WS_SINK2 = 659456 + 65536;

using short8 = __attribute__((ext_vector_type(8))) short;
using f32x4  = __attribute__((ext_vector_type(4))) float;

static __device__ __forceinline__ unsigned short f2bf(float x) {
    unsigned u = __float_as_uint(x);
    unsigned r = 0x7FFFu + ((u >> 16) & 1u);   // RNE
    return (unsigned short)((u + r) >> 16);
}
static __device__ __forceinline__ unsigned pk2(float a, float b) {
    return (unsigned)f2bf(a) | ((unsigned)f2bf(b) << 16);
}
static __device__ __forceinline__ f32x4 mfma16(short8 a, short8 b, f32x4 c) {
    return __builtin_amdgcn_mfma_f32_16x16x32_bf16(a, b, c, 0, 0, 0);
}

// ---- prep: fragment-ordered bf16 B image (unchanged since R6) ----
__global__ __launch_bounds__(256) void vq_prep(const float* __restrict__ Wm,
                                               unsigned char* __restrict__ img)
{
    int id   = blockIdx.x * 256 + threadIdx.x;   // 0..40959
    int lane = id & 63;
    int s    = id >> 6;
    int nt   = s % 5;
    int wcq  = (s / 5) & 3;
    int tk   = s / 20;         // g*16+t
    int g    = tk >> 4;
    int t    = tk & 15;
    int col  = g * V + wcq * 80 + nt * 16 + (lane & 15);
    int kb   = t * 32 + (lane >> 4) * 8;
    unsigned p[4];
#pragma unroll
    for (int jj = 0; jj < 4; ++jj)
        p[jj] = pk2(Wm[(size_t)(kb + 2 * jj) * 640 + col],
                    Wm[(size_t)(kb + 2 * jj + 1) * 640 + col]);
    *reinterpret_cast<uint4*>(img + (size_t)id * 16) = make_uint4(p[0], p[1], p[2], p[3]);
}

// ---- main: bf16 MFMA GEMM (64x320x512), 8 waves, 40-reg accumulator ----
// Unified-regfile theory: acc 40 + misc ~45 => 5-6 waves/SIMD (vs 2-3 at acc=80).
// grid 2048: g=(bid>>3)&1, rblk=(bid&7)|((bid>>4)<<3) (bid,bid+8 same XCD share hs).
__global__ __launch_bounds__(512) void vq_main(
    const float* __restrict__ hs, const unsigned char* __restrict__ img,
    const float* __restrict__ bv, const float* __restrict__ cbv,
    float* __restrict__ out, unsigned int* __restrict__ hist)
{
    __shared__ __align__(16) unsigned char smem[24576];  // A [0,4K) swizzled ; B [4K,24K)

    const int tid  = threadIdx.x;
    const int bid  = blockIdx.x;
    const int g    = (bid >> 3) & 1;
    const int rblk = (bid & 7) | ((bid >> 4) << 3);
    const int r0   = rblk * MT;
    const int w    = tid >> 6;
    const int lane = tid & 63;
    const int l4   = lane & 15;
    const int lc   = lane >> 4;
    const int wc   = w & 3;        // col quarter (80 cols)
    const int h    = w >> 2;       // row half (32 rows)

    f32x4 acc[2][5] = {};

    // A staging: thread -> row tid>>3, k-float4 tid&7 (4 floats -> 4 bf16 = 8B write)
    const int arow = tid >> 3, akq = tid & 7;
    const float* aptr = hs + (size_t)(r0 + arow) * K + akq * 4;
    const int awoff  = (arow * 64 + akq * 8) ^ (((arow >> 1) & 3) << 4);
    const int a_base = h * 2048 + ((l4 * 64 + lc * 16) ^ (((l4 >> 1) & 3) << 4));
    const unsigned char* bsrc = img + (size_t)g * 327680 + (size_t)tid * 16;  // linear panel copy
    const int b_rd = 4096 + wc * 5120;   // + nt*1024 + lane*16

    auto packA = [&](float4 x) {
        *reinterpret_cast<uint2*>(&smem[awoff]) = make_uint2(pk2(x.x, x.y), pk2(x.z, x.w));
    };

    float4 ax = *reinterpret_cast<const float4*>(aptr);   // A(0)

    for (int t = 0; t < NSTEP; ++t) {
        const unsigned char* s = bsrc + (size_t)t * 20480;
        __builtin_amdgcn_global_load_lds(
            (const __attribute__((address_space(1))) void*)(s),
            (__attribute__((address_space(3))) void*)(&smem[4096 + tid * 16]), 16, 0, 0);
        __builtin_amdgcn_global_load_lds(
            (const __attribute__((address_space(1))) void*)(s + 8192),
            (__attribute__((address_space(3))) void*)(&smem[4096 + 8192 + tid * 16]), 16, 0, 0);
        if (tid < 256)
            __builtin_amdgcn_global_load_lds(
                (const __attribute__((address_space(1))) void*)(s + 16384),
                (__attribute__((address_space(3))) void*)(&smem[4096 + 16384 + tid * 16]), 16, 0, 0);
        packA(ax);
        __syncthreads();
        if (t + 1 < NSTEP) ax = *reinterpret_cast<const float4*>(aptr + (t + 1) * 32);
        short8 av[2];
#pragma unroll
        for (int mt = 0; mt < 2; ++mt)
            av[mt] = *reinterpret_cast<const short8*>(&smem[a_base + mt * 1024]);
#pragma unroll
        for (int nt = 0; nt < 5; ++nt) {
            short8 bb = *reinterpret_cast<const short8*>(&smem[b_rd + nt * 1024 + lane * 16]);
            acc[0][nt] = mfma16(av[0], bb, acc[0][nt]);
            acc[1][nt] = mfma16(av[1], bb, acc[1][nt]);
        }
        __syncthreads();
    }

    // ---- epilogue: bias + argmax (D: col=l4, row=lc*4+reg within 16x16 tile) ----
    float biasv[5];
#pragma unroll
    for (int nt = 0; nt < 5; ++nt) biasv[nt] = bv[g * V + wc * 80 + nt * 16 + l4];

    float* red_v = reinterpret_cast<float*>(smem);          // [64][4]
    int*   red_i = reinterpret_cast<int*>(smem + 1024);     // [64][4]
    int*   idx_s = reinterpret_cast<int*>(smem + 2048);     // [64]

#pragma unroll
    for (int mt = 0; mt < 2; ++mt) {
#pragma unroll
        for (int reg = 0; reg < 4; ++reg) {
            float bestv = acc[mt][0][reg] + biasv[0];
            int   besti = wc * 80 + l4;
#pragma unroll
            for (int nt = 1; nt < 5; ++nt) {
                float v = acc[mt][nt][reg] + biasv[nt];
                int   ci = wc * 80 + nt * 16 + l4;
                if (v > bestv) { bestv = v; besti = ci; }
            }
#pragma unroll
            for (int m = 1; m < 16; m <<= 1) {
                float ov = __shfl_xor(bestv, m);
                int   oi = __shfl_xor(besti, m);
                if (ov > bestv || (ov == bestv && oi < besti)) { bestv = ov; besti = oi; }
            }
            if (l4 == 0) {
                int row = h * 32 + mt * 16 + lc * 4 + reg;
                red_v[row * 4 + wc] = bestv;
                red_i[row * 4 + wc] = besti;
            }
        }
    }
    __syncthreads();

    if (tid < MT) {
        float bb = red_v[tid * 4]; int bi = red_i[tid * 4];
#pragma unroll
        for (int c = 1; c < 4; ++c) {
            float v = red_v[tid * 4 + c]; int ii = red_i[tid * 4 + c];
            if (v > bb || (v == bb && ii < bi)) { bb = v; bi = ii; }
        }
        idx_s[tid] = bi;
        atomicAdd(&hist[g * V + bi], 1u);
    }
    __syncthreads();

    // ---- gather: 64 rows x 32 float4 = 2048 chunks, 4 per thread ----
#pragma unroll
    for (int i = 0; i < 4; ++i) {
        int idx = i * 512 + tid;
        int row = idx >> 5;
        int d4  = idx & 31;
        int vi  = idx_s[row];
        float4 val = *reinterpret_cast<const float4*>(&cbv[((size_t)(g * V + vi)) * Dg + d4 * 4]);
        *reinterpret_cast<float4*>(&out[((size_t)(r0 + row)) * (G * Dg) + g * Dg + d4 * 4]) = val;
    }
}

// ---- ablation kernels: same skeleton, d_out untouched, write to ws sink ----
// MODE 1: full staging + barriers, NO MFMA (frags kept live via int xor).
// MODE 2: NO B path (no DMA, no B reads); A chain + MFMA + barriers intact.
template<int MODE>
__global__ __launch_bounds__(512) void vq_abl(
    const float* __restrict__ hs, const unsigned char* __restrict__ img,
    int* __restrict__ sink)
{
    __shared__ __align__(16) unsigned char smem[24576];
    const int tid  = threadIdx.x;
    const int bid  = blockIdx.x;
    const int g    = (bid >> 3) & 1;
    const int rblk = (bid & 7) | ((bid >> 4) << 3);
    const int r0   = rblk * MT;
    const int w    = tid >> 6;
    const int lane = tid & 63;
    const int l4   = lane & 15;
    const int wc   = w & 3;
    const int h    = w >> 2;
    const int lc   = lane >> 4;

    f32x4 acc[2][5] = {};
    int csum = 0;

    const int arow = tid >> 3, akq = tid & 7;
    const float* aptr = hs + (size_t)(r0 + arow) * K + akq * 4;
    const int awoff  = (arow * 64 + akq * 8) ^ (((arow >> 1) & 3) << 4);
    const int a_base = h * 2048 + ((l4 * 64 + lc * 16) ^ (((l4 >> 1) & 3) << 4));
    const unsigned char* bsrc = img + (size_t)g * 327680 + (size_t)tid * 16;
    const int b_rd = 4096 + wc * 5120;

    float4 ax = *reinterpret_cast<const float4*>(aptr);

    for (int t = 0; t < NSTEP; ++t) {
        if (MODE != 2) {
            const unsigned char* s = bsrc + (size_t)t * 20480;
            __builtin_amdgcn_global_load_lds(
                (const __attribute__((address_space(1))) void*)(s),
                (__attribute__((address_space(3))) void*)(&smem[4096 + tid * 16]), 16, 0, 0);
            __builtin_amdgcn_global_load_lds(
                (const __attribute__((address_space(1))) void*)(s + 8192),
                (__attribute__((address_space(3))) void*)(&smem[4096 + 8192 + tid * 16]), 16, 0, 0);
            if (tid < 256)
                __builtin_amdgcn_global_load_lds(
                    (const __attribute__((address_space(1))) void*)(s + 16384),
                    (__attribute__((address_space(3))) void*)(&smem[4096 + 16384 + tid * 16]), 16, 0, 0);
        }
        *reinterpret_cast<uint2*>(&smem[awoff]) = make_uint2(pk2(ax.x, ax.y), pk2(ax.z, ax.w));
        __syncthreads();
        if (t + 1 < NSTEP) ax = *reinterpret_cast<const float4*>(aptr + (t + 1) * 32);
        short8 av[2];
#pragma unroll
        for (int mt = 0; mt < 2; ++mt)
            av[mt] = *reinterpret_cast<const short8*>(&smem[a_base + mt * 1024]);
#pragma unroll
        for (int nt = 0; nt < 5; ++nt) {
            if (MODE == 1) {
                short8 bb = *reinterpret_cast<const short8*>(&smem[b_rd + nt * 1024 + lane * 16]);
                csum ^= (int)bb[0] ^ (int)bb[2] ^ (int)bb[4] ^ (int)bb[6];
            } else {  // MODE 2: MFMA on A-only frags
                acc[0][nt] = mfma16(av[0], av[0], acc[0][nt]);
                acc[1][nt] = mfma16(av[1], av[1], acc[1][nt]);
            }
        }
        if (MODE == 1) {
            csum ^= (int)av[0][0] ^ (int)av[0][2] ^ (int)av[0][4] ^ (int)av[0][6]
                  ^ (int)av[1][0] ^ (int)av[1][2] ^ (int)av[1][4] ^ (int)av[1][6];
        }
        __syncthreads();
    }

    if (MODE == 2) {
        float fs = 0.f;
#pragma unroll
        for (int mt = 0; mt < 2; ++mt)
#pragma unroll
            for (int nt = 0; nt < 5; ++nt) fs += acc[mt][nt][0] + acc[mt][nt][3];
        csum = __float_as_int(fs);
    }
    sink[((bid & 31) << 9) | tid] = csum;   // racy across blocks; never read into d_out
}

// Perplexity from histogram: one wave.
__global__ void vq_ppl(const unsigned int* __restrict__ hist, float* __restrict__ outp)
{
    int lane = threadIdx.x;  // 64
    float ppl = 0.0f;
    for (int g = 0; g < G; ++g) {
        float local = 0.0f;
        for (int v = lane; v < V; v += 64) {
            float m = (float)hist[g * V + v] * (1.0f / (float)BT);
            local += m * logf(m + 1e-7f);
        }
#pragma unroll
        for (int off = 32; off; off >>= 1) local += __shfl_down(local, off);
        if (lane == 0) ppl += expf(-local);
    }
    if (lane == 0) outp[0] = ppl;
}

extern "C" void kernel_launch(void* const* d_in, const int* in_sizes, int n_in,
                              void* d_out, int out_size, void* d_ws, size_t ws_size,
                              hipStream_t stream)
{
    const float* hs  = (const float*)d_in[0];   // (65536, 512)
    const float* Wm  = (const float*)d_in[1];   // (512, 640)
    const float* bv  = (const float*)d_in[2];   // (640,)
    const float* cbv = (const float*)d_in[3];   // (640, 128)
    float* out = (float*)d_out;                 // 65536*256 floats + 1 float perplexity

    unsigned int*  hist  = (unsigned int*)d_ws;
    unsigned char* img   = (unsigned char*)d_ws + WS_IMG;
    int*           sink1 = (int*)((char*)d_ws + WS_SINK1);
    int*           sink2 = (int*)((char*)d_ws + WS_SINK2);

    hipMemsetAsync(d_ws, 0, G * V * sizeof(unsigned int), stream);
    vq_prep<<<160, 256, 0, stream>>>(Wm, img);
    vq_main<<<2048, 512, 0, stream>>>(hs, img, bv, cbv, out, hist);
    vq_abl<1><<<2048, 512, 0, stream>>>(hs, img, sink1);   // skeleton, no MFMA
    vq_abl<2><<<2048, 512, 0, stream>>>(hs, img, sink2);   // no B path
    vq_ppl<<<1, 64, 0, stream>>>(hist, out + (size_t)BT * G * Dg);
}

// Round 12
// 103.403 us; speedup vs baseline: 1.6742x; 1.6742x over previous
//
#include <hip/hip_runtime.h>
#include <hip/hip_bf16.h>

// B=16,S=4096,H=512 ; G=2,V=320,D=256 (Dg=128)
constexpr int BT = 65536;
constexpr int K  = 512;
constexpr int V  = 320;
constexpr int G  = 2;
constexpr int Dg = 128;
constexpr int MT = 64;           // rows per block; 8 waves = 2 row-halves x 4 col-quarters
constexpr int NSTEP = 8;         // K/64  (BK=64: R12's single variable vs R11)
constexpr size_t WS_IMG = 4096;  // frag-ordered B img (640 KB)

using short8 = __attribute__((ext_vector_type(8))) short;
using f32x4  = __attribute__((ext_vector_type(4))) float;

static __device__ __forceinline__ unsigned short f2bf(float x) {
    unsigned u = __float_as_uint(x);
    unsigned r = 0x7FFFu + ((u >> 16) & 1u);   // RNE
    return (unsigned short)((u + r) >> 16);
}
static __device__ __forceinline__ unsigned pk2(float a, float b) {
    return (unsigned)f2bf(a) | ((unsigned)f2bf(b) << 16);
}
static __device__ __forceinline__ f32x4 mfma16(short8 a, short8 b, f32x4 c) {
    return __builtin_amdgcn_mfma_f32_16x16x32_bf16(a, b, c, 0, 0, 0);
}

// ---- prep: fragment-ordered bf16 B image (unchanged since R6) ----
// chunk index = (((g*16+t)*4+wc)*5+nt)*64+lane, 16 B each =
// bf16 of W[t*32+(lane>>4)*8 .. +7][g*320 + wc*80+nt*16+(lane&15)]
__global__ __launch_bounds__(256) void vq_prep(const float* __restrict__ Wm,
                                               unsigned char* __restrict__ img)
{
    int id   = blockIdx.x * 256 + threadIdx.x;   // 0..40959
    int lane = id & 63;
    int s    = id >> 6;
    int nt   = s % 5;
    int wcq  = (s / 5) & 3;
    int tk   = s / 20;         // g*16+t
    int g    = tk >> 4;
    int t    = tk & 15;
    int col  = g * V + wcq * 80 + nt * 16 + (lane & 15);
    int kb   = t * 32 + (lane >> 4) * 8;
    unsigned p[4];
#pragma unroll
    for (int jj = 0; jj < 4; ++jj)
        p[jj] = pk2(Wm[(size_t)(kb + 2 * jj) * 640 + col],
                    Wm[(size_t)(kb + 2 * jj + 1) * 640 + col]);
    *reinterpret_cast<uint4*>(img + (size_t)id * 16) = make_uint4(p[0], p[1], p[2], p[3]);
}

// ---- main: bf16 MFMA GEMM (64x320x512), BK=64, 8 k-steps, 8 waves ----
// LDS 48KB single-buf: A [0,8K) swizzled [64 rows][64 k] bf16 ; B [8K,48K) = linear
// copy of two 20KB frag-ordered panels (t=2s, 2s+1).
// grid 2048: g=(bid>>3)&1, rblk=(bid&7)|((bid>>4)<<3) (bid,bid+8 same XCD share hs).
__global__ __launch_bounds__(512) void vq_main(
    const float* __restrict__ hs, const unsigned char* __restrict__ img,
    const float* __restrict__ bv, const float* __restrict__ cbv,
    float* __restrict__ out, unsigned int* __restrict__ hist)
{
    __shared__ __align__(16) unsigned char smem[49152];

    const int tid  = threadIdx.x;
    const int bid  = blockIdx.x;
    const int g    = (bid >> 3) & 1;
    const int rblk = (bid & 7) | ((bid >> 4) << 3);
    const int r0   = rblk * MT;
    const int w    = tid >> 6;
    const int lane = tid & 63;
    const int l4   = lane & 15;
    const int lc   = lane >> 4;
    const int wc   = w & 3;        // col quarter (80 cols)
    const int h    = w >> 2;       // row half (32 rows)

    f32x4 acc[2][5] = {};

    // A staging: thread -> row tid>>3 (0..63), q=tid&7 -> 8 floats (k = q*8..q*8+7)
    const int arow = tid >> 3, akq = tid & 7;
    const float* aptr = hs + (size_t)(r0 + arow) * K + akq * 8;
    const int awoff = (arow * 128 + akq * 16) ^ ((arow & 7) << 4);
    // A frag read: row = h*32 + mt*16 + l4 (row&7 == l4&7), k = kk*32 + lc*8
    const int a_base = ((h * 32 + l4) * 128 + lc * 16) ^ ((l4 & 7) << 4);  // + mt*2048 + kk*64
    // B: linear double-panel copy; read offsets per (kk,wc,nt,lane)
    const unsigned char* bsrc = img + (size_t)g * 327680 + (size_t)tid * 16;
    const int b_rd = 8192 + wc * 5120 + lane * 16;   // + kk*20480 + nt*1024

    auto packA = [&](float4 x, float4 y) {
        *reinterpret_cast<uint4*>(&smem[awoff]) =
            make_uint4(pk2(x.x, x.y), pk2(x.z, x.w), pk2(y.x, y.y), pk2(y.z, y.w));
    };

    // prologue: A(0) in flight
    float4 ax = *reinterpret_cast<const float4*>(aptr);
    float4 ay = *reinterpret_cast<const float4*>(aptr + 4);

    for (int s = 0; s < NSTEP; ++s) {
        // ---- stage: B double-panel (40KB) via LDS-DMA, A (8KB) convert+write ----
        const unsigned char* bs = bsrc + (size_t)s * 40960;
#pragma unroll
        for (int i = 0; i < 5; ++i)
            __builtin_amdgcn_global_load_lds(
                (const __attribute__((address_space(1))) void*)(bs + i * 8192),
                (__attribute__((address_space(3))) void*)(&smem[8192 + i * 8192 + tid * 16]),
                16, 0, 0);
        packA(ax, ay);                    // auto-waits A(s) only
        __syncthreads();                  // drains B DMA + LDS writes
        // ---- compute; A(s+1) issued first so HBM latency hides under MFMA ----
        if (s + 1 < NSTEP) {
            ax = *reinterpret_cast<const float4*>(aptr + (s + 1) * 64);
            ay = *reinterpret_cast<const float4*>(aptr + (s + 1) * 64 + 4);
        }
#pragma unroll
        for (int kk = 0; kk < 2; ++kk) {          // t = 2s+kk, same t-order as R11
            short8 av[2];
#pragma unroll
            for (int mt = 0; mt < 2; ++mt)
                av[mt] = *reinterpret_cast<const short8*>(
                    &smem[a_base + mt * 2048 + kk * 64]);
#pragma unroll
            for (int nt = 0; nt < 5; ++nt) {
                short8 bb = *reinterpret_cast<const short8*>(
                    &smem[b_rd + kk * 20480 + nt * 1024]);
                acc[0][nt] = mfma16(av[0], bb, acc[0][nt]);
                acc[1][nt] = mfma16(av[1], bb, acc[1][nt]);
            }
        }
        __syncthreads();                  // buffer reuse guard
    }

    // ---- epilogue: bias + argmax (D: col=l4, row=lc*4+reg within 16x16 tile) ----
    float biasv[5];
#pragma unroll
    for (int nt = 0; nt < 5; ++nt) biasv[nt] = bv[g * V + wc * 80 + nt * 16 + l4];

    float* red_v = reinterpret_cast<float*>(smem);          // [64][4]
    int*   red_i = reinterpret_cast<int*>(smem + 1024);     // [64][4]
    int*   idx_s = reinterpret_cast<int*>(smem + 2048);     // [64]

#pragma unroll
    for (int mt = 0; mt < 2; ++mt) {
#pragma unroll
        for (int reg = 0; reg < 4; ++reg) {
            float bestv = acc[mt][0][reg] + biasv[0];
            int   besti = wc * 80 + l4;
#pragma unroll
            for (int nt = 1; nt < 5; ++nt) {
                float v = acc[mt][nt][reg] + biasv[nt];
                int   ci = wc * 80 + nt * 16 + l4;
                if (v > bestv) { bestv = v; besti = ci; }
            }
#pragma unroll
            for (int m = 1; m < 16; m <<= 1) {
                float ov = __shfl_xor(bestv, m);
                int   oi = __shfl_xor(besti, m);
                if (ov > bestv || (ov == bestv && oi < besti)) { bestv = ov; besti = oi; }
            }
            if (l4 == 0) {
                int row = h * 32 + mt * 16 + lc * 4 + reg;
                red_v[row * 4 + wc] = bestv;
                red_i[row * 4 + wc] = besti;
            }
        }
    }
    __syncthreads();

    if (tid < MT) {
        float bb = red_v[tid * 4]; int bi = red_i[tid * 4];
#pragma unroll
        for (int c = 1; c < 4; ++c) {
            float v = red_v[tid * 4 + c]; int ii = red_i[tid * 4 + c];
            if (v > bb || (v == bb && ii < bi)) { bb = v; bi = ii; }
        }
        idx_s[tid] = bi;
        atomicAdd(&hist[g * V + bi], 1u);
    }
    __syncthreads();

    // ---- gather: 64 rows x 32 float4 = 2048 chunks, 4 per thread ----
#pragma unroll
    for (int i = 0; i < 4; ++i) {
        int idx = i * 512 + tid;
        int row = idx >> 5;
        int d4  = idx & 31;
        int vi  = idx_s[row];
        float4 val = *reinterpret_cast<const float4*>(&cbv[((size_t)(g * V + vi)) * Dg + d4 * 4]);
        *reinterpret_cast<float4*>(&out[((size_t)(r0 + row)) * (G * Dg) + g * Dg + d4 * 4]) = val;
    }
}

// Perplexity from histogram: one wave.
__global__ void vq_ppl(const unsigned int* __restrict__ hist, float* __restrict__ outp)
{
    int lane = threadIdx.x;  // 64
    float ppl = 0.0f;
    for (int g = 0; g < G; ++g) {
        float local = 0.0f;
        for (int v = lane; v < V; v += 64) {
            float m = (float)hist[g * V + v] * (1.0f / (float)BT);
            local += m * logf(m + 1e-7f);
        }
#pragma unroll
        for (int off = 32; off; off >>= 1) local += __shfl_down(local, off);
        if (lane == 0) ppl += expf(-local);
    }
    if (lane == 0) outp[0] = ppl;
}

extern "C" void kernel_launch(void* const* d_in, const int* in_sizes, int n_in,
                              void* d_out, int out_size, void* d_ws, size_t ws_size,
                              hipStream_t stream)
{
    const float* hs  = (const float*)d_in[0];   // (65536, 512)
    const float* Wm  = (const float*)d_in[1];   // (512, 640)
    const float* bv  = (const float*)d_in[2];   // (640,)
    const float* cbv = (const float*)d_in[3];   // (640, 128)
    float* out = (float*)d_out;                 // 65536*256 floats + 1 float perplexity

    unsigned int*  hist = (unsigned int*)d_ws;
    unsigned char* img  = (unsigned char*)d_ws + WS_IMG;

    hipMemsetAsync(d_ws, 0, G * V * sizeof(unsigned int), stream);
    vq_prep<<<160, 256, 0, stream>>>(Wm, img);
    vq_main<<<2048, 512, 0, stream>>>(hs, img, bv, cbv, out, hist);
    vq_ppl<<<1, 64, 0, stream>>>(hist, out + (size_t)BT * G * Dg);
}